// Round 8
// baseline (1069.879 us; speedup 1.0000x reference)
//
#include <hip/hip_runtime.h>
#include <hip/hip_bf16.h>
#include <cstdint>
#include <cstddef>

#define NNODES 50000
#define NEDGES 800000
#define NREL 8
#define DIM 128
#define NOUT 1024  // NREL*DIM concat output dim of k_xr
#define NEG_SLOPE 0.2f

typedef __attribute__((ext_vector_type(8))) short short8;
typedef __attribute__((ext_vector_type(4))) float f32x4;

// bf16 helpers (RNE)
static __device__ __forceinline__ short f2bf(float v) {
  union { float f; unsigned u; } c; c.f = v;
  unsigned u = c.u;
  unsigned r = (u + 0x7fffu + ((u >> 16) & 1u)) >> 16;
  return (short)r;
}
static __device__ __forceinline__ float bf2f(short s) {
  union { unsigned u; float f; } c; c.u = ((unsigned)(unsigned short)s) << 16;
  return c.f;
}

// ======================= preprocessing: CSR by (dst, etype) =======================

__global__ void k_hist(const int* __restrict__ ei, const int* __restrict__ et,
                       int* __restrict__ cnt, int E) {
  int e = blockIdx.x * 256 + threadIdx.x;
  if (e < E) {
    int d = ei[E + e];
    int t = et[e];
    atomicAdd(&cnt[d * NREL + t], 1);
  }
}

__global__ void k_scan_reduce(const int* __restrict__ cnt, int* __restrict__ sums, int n) {
  __shared__ int sd[256];
  int base = blockIdx.x * 4096;
  int t = threadIdx.x;
  int acc = 0;
  for (int i = t; i < 4096; i += 256) {
    int idx = base + i;
    if (idx < n) acc += cnt[idx];
  }
  sd[t] = acc; __syncthreads();
  for (int s = 128; s > 0; s >>= 1) {
    if (t < s) sd[t] += sd[t + s];
    __syncthreads();
  }
  if (t == 0) sums[blockIdx.x] = sd[0];
}

// exclusive scan of up to 128 block sums, parallel
__global__ void k_scan_top(int* sums, int nb) {
  __shared__ int sd[128];
  int t = threadIdx.x;
  int v = (t < nb) ? sums[t] : 0;
  sd[t] = v; __syncthreads();
  for (int s = 1; s < 128; s <<= 1) {
    int u = (t >= s) ? sd[t - s] : 0;
    __syncthreads();
    sd[t] += u;
    __syncthreads();
  }
  if (t < nb) sums[t] = sd[t] - v;  // exclusive
}

__global__ void k_scan_final(const int* __restrict__ cnt, const int* __restrict__ sums,
                             int* __restrict__ offs, int* __restrict__ cur,
                             int n, int E) {
  __shared__ int sd[256];
  int base = blockIdx.x * 4096;
  int t = threadIdx.x;
  int run = sums[blockIdx.x];
  for (int c = 0; c < 16; c++) {
    int idx = base + c * 256 + t;
    int v = (idx < n) ? cnt[idx] : 0;
    sd[t] = v; __syncthreads();
    for (int s = 1; s < 256; s <<= 1) {
      int u = (t >= s) ? sd[t - s] : 0;
      __syncthreads();
      sd[t] += u;
      __syncthreads();
    }
    if (idx < n) {
      int e0 = run + sd[t] - v;  // exclusive
      offs[idx] = e0;
      cur[idx] = e0;
    }
    run += sd[255];
    __syncthreads();
  }
  if (blockIdx.x == 0 && t == 0) offs[n] = E;
}

__global__ void k_scatter(const int* __restrict__ ei, const int* __restrict__ et,
                          int* __restrict__ cursor, int* __restrict__ pk, int E) {
  int e = blockIdx.x * 256 + threadIdx.x;
  if (e < E) {
    int s = ei[e];       // src < 50000 fits in 16 bits
    int d = ei[E + e];
    int t = et[e];
    int pos = atomicAdd(&cursor[d * NREL + t], 1);
    pk[pos] = s | (t << 16);
  }
}

// ======================= per-layer kernels =======================

// Merged: blocks 0..63 split Wcat into fragment-major bf16 hi/lo; blocks 64..71
// compute wq/wk.  Frag id = (n16*4 + kc)*64 + l: n = n16*16 + (l&15),
// k = kc*32 + (l>>4)*8 + j.
__global__ void k_wprep(const float* __restrict__ W, const float* __restrict__ q,
                        const float* __restrict__ k, short* __restrict__ Wfh,
                        short* __restrict__ Wfl, float* __restrict__ wq,
                        float* __restrict__ wk) {
  int b = blockIdx.x;
  if (b < 64) {
    int id = b * 256 + threadIdx.x;  // 0..16383
    int l = id & 63;
    int kc = (id >> 6) & 3;
    int n16 = id >> 8;
    int n = n16 * 16 + (l & 15);      // 0..1023
    int r = n >> 7, nn = n & 127;
    int k0 = kc * 32 + (l >> 4) * 8;  // 0..127
    short8 vh, vl;
#pragma unroll
    for (int j = 0; j < 8; j++) {
      float v = W[((size_t)r * DIM + k0 + j) * DIM + nn];
      short h = f2bf(v);
      vh[j] = h;
      vl[j] = f2bf(v - bf2f(h));
    }
    ((short8*)Wfh)[id] = vh;
    ((short8*)Wfl)[id] = vl;
  } else {
    int id = (b - 64) * 256 + threadIdx.x;  // 0..2047
    int which = id >> 10;       // 0 = q, 1 = k
    int rc = id & 1023;         // r*128 + c
    const float* wrow = W + (size_t)rc * DIM;
    const float* v = which ? k : q;
    float acc = 0.f;
#pragma unroll 8
    for (int d = 0; d < DIM; d++) acc += wrow[d] * v[d];
    (which ? wk : wq)[rc] = acc;
  }
}

// qp[n][r] = x[n]·wq[r], kp[n][r] = x[n]·wk[r]. One wave per node.
__global__ void k_qk(const float* __restrict__ x, const float* __restrict__ wq,
                     const float* __restrict__ wk, float* __restrict__ qp,
                     float* __restrict__ kp, int N) {
  int wid = (blockIdx.x * blockDim.x + threadIdx.x) >> 6;
  int lane = threadIdx.x & 63;
  if (wid >= N) return;
  float x0 = x[(size_t)wid * DIM + lane];
  float x1 = x[(size_t)wid * DIM + 64 + lane];
#pragma unroll
  for (int r = 0; r < NREL; r++) {
    float aq = x0 * wq[r * DIM + lane] + x1 * wq[r * DIM + 64 + lane];
    float ak = x0 * wk[r * DIM + lane] + x1 * wk[r * DIM + 64 + lane];
    for (int s = 32; s > 0; s >>= 1) {
      aq += __shfl_xor(aq, s);
      ak += __shfl_xor(ak, s);
    }
    if (lane == 0) {
      qp[(size_t)wid * NREL + r] = aq;
      kp[(size_t)wid * NREL + r] = ak;
    }
  }
}

// ======================= k_xr: xr = hin @ Wcat, split-bf16 MFMA =======================
// [M=50000,K=128] @ [128,1024] -> fp32 xr [M][1024].  Block = 64m x 128n tile;
// 4 waves, wave w covers n in [nb*128 + w*32, +32).  A staged in LDS as
// pre-split bf16 hi/lo planes with XOR swizzle (conflict-free ds_read_b128).
__global__ __launch_bounds__(256, 4) void k_xr(
    const float* __restrict__ A, const short* __restrict__ Wfh,
    const short* __restrict__ Wfl, float* __restrict__ xr, int M, int nmt) {
  __shared__ char sAh[64 * 256];
  __shared__ char sAl[64 * 256];
  // bijective XCD-chunk swizzle: the 8 nb-blocks of one m-tile share an XCD L2
  int lin = blockIdx.x;              // 0 .. nmt*8-1
  int xcd = lin & 7, pos = lin >> 3;
  int g = xcd * nmt + pos;
  int mt0 = g >> 3, nb = g & 7;
  int m0 = mt0 * 64;
  int t = threadIdx.x, w = t >> 6, l = t & 63;

  // ---- stage A tile: 64 rows x 128 fp32 -> bf16 hi/lo planes, swizzled ----
  {
    int row = t >> 2, q4 = t & 3;
    int m = m0 + row;
    int sw = (row & 7) << 4;
    const float4* src = (const float4*)(A + (size_t)m * DIM + q4 * 32);
    float4 z = make_float4(0.f, 0.f, 0.f, 0.f);
#pragma unroll
    for (int u = 0; u < 4; u++) {
      float4 va = (m < M) ? src[2 * u] : z;
      float4 vb = (m < M) ? src[2 * u + 1] : z;
      float vv[8] = {va.x, va.y, va.z, va.w, vb.x, vb.y, vb.z, vb.w};
      short8 hh, ll;
#pragma unroll
      for (int j = 0; j < 8; j++) {
        short h = f2bf(vv[j]);
        hh[j] = h;
        ll[j] = f2bf(vv[j] - bf2f(h));
      }
      int off = row * 256 + ((q4 * 64 + u * 16) ^ sw);
      *(short8*)(sAh + off) = hh;
      *(short8*)(sAl + off) = ll;
    }
  }
  __syncthreads();

  f32x4 acc[4][2];
  f32x4 zero = {0.f, 0.f, 0.f, 0.f};
#pragma unroll
  for (int mt = 0; mt < 4; mt++)
#pragma unroll
    for (int nt = 0; nt < 2; nt++) acc[mt][nt] = zero;

  int r16 = l & 15, hi16 = l >> 4;
  int n16base = nb * 8 + w * 2;
#pragma unroll
  for (int kc = 0; kc < 4; kc++) {
    short8 fsh[4], fsl[4];
#pragma unroll
    for (int mt = 0; mt < 4; mt++) {
      int row = mt * 16 + r16;
      int off = row * 256 + ((kc * 64 + hi16 * 16) ^ ((row & 7) << 4));
      fsh[mt] = *(const short8*)(sAh + off);
      fsl[mt] = *(const short8*)(sAl + off);
    }
#pragma unroll
    for (int nt = 0; nt < 2; nt++) {
      size_t fid = ((size_t)(n16base + nt) * 4 + kc) * 64 + l;
      short8 ah = ((const short8*)Wfh)[fid];
      short8 al = ((const short8*)Wfl)[fid];
#pragma unroll
      for (int mt = 0; mt < 4; mt++) {
        acc[mt][nt] = __builtin_amdgcn_mfma_f32_16x16x32_bf16(ah, fsh[mt], acc[mt][nt], 0, 0, 0);
        acc[mt][nt] = __builtin_amdgcn_mfma_f32_16x16x32_bf16(ah, fsl[mt], acc[mt][nt], 0, 0, 0);
        acc[mt][nt] = __builtin_amdgcn_mfma_f32_16x16x32_bf16(al, fsh[mt], acc[mt][nt], 0, 0, 0);
      }
    }
  }
  // ---- epilogue: D col(l&15)=m, row((l>>4)*4+j)=n ----
#pragma unroll
  for (int mt = 0; mt < 4; mt++) {
    int m = m0 + mt * 16 + r16;
    if (m >= M) continue;
#pragma unroll
    for (int nt = 0; nt < 2; nt++) {
      int n = nb * 128 + w * 32 + nt * 16 + hi16 * 4;
      f32x4 a = acc[mt][nt];
      float4 o; o.x = a.x; o.y = a.y; o.z = a.z; o.w = a.w;
      *(float4*)(xr + (size_t)m * NOUT + n) = o;
    }
  }
}

// ======================= k_agg_out: online softmax + gather-aggregate ==============
// One wave per dst node. out[n][c] = relu_opt( sum_e alpha_e * xr[src_e][t_e*128+c] + b[c] )
__global__ void k_agg_out(const float* __restrict__ xr, const float* __restrict__ qp,
                          const float* __restrict__ kp, const int* __restrict__ offs,
                          const int* __restrict__ pk, const float* __restrict__ bias,
                          float* __restrict__ out, int N, int relu) {
  int wid = (blockIdx.x * blockDim.x + threadIdx.x) >> 6;
  int lane = threadIdx.x & 63;
  if (wid >= N) return;
  int base = wid * NREL;
  int start = offs[base], end = offs[base + NREL];
  float a0 = 0.f, a1 = 0.f;
  if (start < end) {
    // ---- sweep 1: online (max, sum) per lane, then wave merge ----
    float m = -1e30f, s = 0.f;
    for (int i = start + lane; i < end; i += 64) {
      int p = pk[i];
      int src = p & 0xffff, tt = p >> 16;
      float a = qp[base + tt] + kp[src * NREL + tt];
      a = (a > 0.f) ? a : NEG_SLOPE * a;
      float mn = fmaxf(m, a);
      s = s * __expf(m - mn) + __expf(a - mn);
      m = mn;
    }
    for (int d = 32; d > 0; d >>= 1) {
      float mo = __shfl_xor(m, d);
      float so = __shfl_xor(s, d);
      float mn = fmaxf(m, mo);
      s = s * __expf(m - mn) + so * __expf(mo - mn);
      m = mn;
    }
    float inv = 1.f / (s + 1e-16f);
    // ---- sweep 2: weighted gather, 4-deep ----
    int i = start;
    for (; i + 4 <= end; i += 4) {
      int p0 = pk[i], p1 = pk[i + 1], p2 = pk[i + 2], p3 = pk[i + 3];
      float2 xv0 = ((const float2*)(xr + (((size_t)(p0 & 0xffff)) * NREL + (p0 >> 16)) * DIM))[lane];
      float2 xv1 = ((const float2*)(xr + (((size_t)(p1 & 0xffff)) * NREL + (p1 >> 16)) * DIM))[lane];
      float2 xv2 = ((const float2*)(xr + (((size_t)(p2 & 0xffff)) * NREL + (p2 >> 16)) * DIM))[lane];
      float2 xv3 = ((const float2*)(xr + (((size_t)(p3 & 0xffff)) * NREL + (p3 >> 16)) * DIM))[lane];
      float aa0 = qp[base + (p0 >> 16)] + kp[(p0 & 0xffff) * NREL + (p0 >> 16)];
      float aa1 = qp[base + (p1 >> 16)] + kp[(p1 & 0xffff) * NREL + (p1 >> 16)];
      float aa2 = qp[base + (p2 >> 16)] + kp[(p2 & 0xffff) * NREL + (p2 >> 16)];
      float aa3 = qp[base + (p3 >> 16)] + kp[(p3 & 0xffff) * NREL + (p3 >> 16)];
      aa0 = (aa0 > 0.f) ? aa0 : NEG_SLOPE * aa0;
      aa1 = (aa1 > 0.f) ? aa1 : NEG_SLOPE * aa1;
      aa2 = (aa2 > 0.f) ? aa2 : NEG_SLOPE * aa2;
      aa3 = (aa3 > 0.f) ? aa3 : NEG_SLOPE * aa3;
      float w0 = __expf(aa0 - m) * inv;
      float w1 = __expf(aa1 - m) * inv;
      float w2 = __expf(aa2 - m) * inv;
      float w3 = __expf(aa3 - m) * inv;
      a0 = fmaf(w0, xv0.x, a0); a1 = fmaf(w0, xv0.y, a1);
      a0 = fmaf(w1, xv1.x, a0); a1 = fmaf(w1, xv1.y, a1);
      a0 = fmaf(w2, xv2.x, a0); a1 = fmaf(w2, xv2.y, a1);
      a0 = fmaf(w3, xv3.x, a0); a1 = fmaf(w3, xv3.y, a1);
    }
    for (; i < end; i++) {
      int p = pk[i];
      int src = p & 0xffff, tt = p >> 16;
      float2 xv = ((const float2*)(xr + ((size_t)src * NREL + tt) * DIM))[lane];
      float a = qp[base + tt] + kp[src * NREL + tt];
      a = (a > 0.f) ? a : NEG_SLOPE * a;
      float wg = __expf(a - m) * inv;
      a0 = fmaf(wg, xv.x, a0);
      a1 = fmaf(wg, xv.y, a1);
    }
  }
  float2 bv = ((const float2*)bias)[lane];
  a0 += bv.x; a1 += bv.y;
  if (relu) { a0 = fmaxf(a0, 0.f); a1 = fmaxf(a1, 0.f); }
  float2 o; o.x = a0; o.y = a1;
  ((float2*)(out + (size_t)wid * DIM))[lane] = o;
}

// ======================= launcher =======================

extern "C" void kernel_launch(void* const* d_in, const int* in_sizes, int n_in,
                              void* d_out, int out_size, void* d_ws, size_t ws_size,
                              hipStream_t stream) {
  const float* x = (const float*)d_in[0];
  const int* ei = (const int*)d_in[1];
  const int* et = (const int*)d_in[2];
  const float* Wl3[3] = {(const float*)d_in[3], (const float*)d_in[7], (const float*)d_in[11]};
  const float* ql[3] = {(const float*)d_in[4], (const float*)d_in[8], (const float*)d_in[12]};
  const float* kl[3] = {(const float*)d_in[5], (const float*)d_in[9], (const float*)d_in[13]};
  const float* bl[3] = {(const float*)d_in[6], (const float*)d_in[10], (const float*)d_in[14]};
  float* out = (float*)d_out;

  char* w = (char*)d_ws;
  auto alloc = [&](size_t bytes) -> char* {
    char* p = w;
    w += (bytes + 255) & ~(size_t)255;
    return p;
  };
  const int NK = NNODES * NREL;
  float* xr = (float*)alloc((size_t)NNODES * NOUT * 4);  // 204.8 MB
  int* cnt = (int*)alloc((size_t)NK * 4);
  int* offs = (int*)alloc((size_t)(NK + 1) * 4);
  int* cursor = (int*)alloc((size_t)NK * 4);
  int* sums = (int*)alloc(256 * 4);
  int* pk = (int*)alloc((size_t)NEDGES * 4);
  float* wq = (float*)alloc((size_t)NREL * DIM * 4);
  float* wk = (float*)alloc((size_t)NREL * DIM * 4);
  float* qp = (float*)alloc((size_t)NNODES * NREL * 4);
  float* kp = (float*)alloc((size_t)NNODES * NREL * 4);
  short* Wfh = (short*)alloc((size_t)DIM * NOUT * 2);
  short* Wfl = (short*)alloc((size_t)DIM * NOUT * 2);
  float* h1 = (float*)alloc((size_t)NNODES * DIM * 4);
  float* h2 = (float*)alloc((size_t)NNODES * DIM * 4);

  // ---- build CSR sorted by (dst, etype), once (shared by all 3 layers) ----
  hipMemsetAsync(cnt, 0, (size_t)NK * 4, stream);
  k_hist<<<(NEDGES + 255) / 256, 256, 0, stream>>>(ei, et, cnt, NEDGES);
  int nchunk = (NK + 4095) / 4096;  // 98
  k_scan_reduce<<<nchunk, 256, 0, stream>>>(cnt, sums, NK);
  k_scan_top<<<1, 128, 0, stream>>>(sums, nchunk);
  k_scan_final<<<nchunk, 256, 0, stream>>>(cnt, sums, offs, cursor, NK, NEDGES);
  k_scatter<<<(NEDGES + 255) / 256, 256, 0, stream>>>(ei, et, cursor, pk, NEDGES);

  // ---- 3 RGAT layers ----
  const float* hin = x;
  float* houts[3] = {h1, h2, out};
  const int nmt = (NNODES + 63) / 64;  // 782
  for (int l = 0; l < 3; l++) {
    k_wprep<<<72, 256, 0, stream>>>(Wl3[l], ql[l], kl[l], Wfh, Wfl, wq, wk);
    k_qk<<<(NNODES + 3) / 4, 256, 0, stream>>>(hin, wq, wk, qp, kp, NNODES);
    k_xr<<<nmt * 8, 256, 0, stream>>>(hin, Wfh, Wfl, xr, NNODES, nmt);
    k_agg_out<<<(NNODES + 3) / 4, 256, 0, stream>>>(xr, qp, kp, offs, pk, bl[l],
                                                    houts[l], NNODES, l < 2 ? 1 : 0);
    hin = houts[l];
  }
}

// Round 9
// 835.233 us; speedup vs baseline: 1.2809x; 1.2809x over previous
//
#include <hip/hip_runtime.h>
#include <hip/hip_bf16.h>
#include <cstdint>
#include <cstddef>

#define NNODES 50000
#define NEDGES 800000
#define NREL 8
#define DIM 128
#define NOUT 1024  // NREL*DIM concat output dim of k_xr
#define NEG_SLOPE 0.2f
#define NFRAG 16640  // (64 W n16-groups + 1 qk-group) * 4 kc * 64 lanes, short8 units

typedef __attribute__((ext_vector_type(8))) short short8;
typedef __attribute__((ext_vector_type(4))) float f32x4;

// bf16 helpers (RNE)
static __device__ __forceinline__ short f2bf(float v) {
  union { float f; unsigned u; } c; c.f = v;
  unsigned u = c.u;
  unsigned r = (u + 0x7fffu + ((u >> 16) & 1u)) >> 16;
  return (short)r;
}
static __device__ __forceinline__ float bf2f(short s) {
  union { unsigned u; float f; } c; c.u = ((unsigned)(unsigned short)s) << 16;
  return c.f;
}

// ======================= preprocessing: CSR by (dst, etype) =======================

__global__ void k_hist(const int* __restrict__ ei, const int* __restrict__ et,
                       int* __restrict__ cnt, int E) {
  int e = blockIdx.x * 256 + threadIdx.x;
  if (e < E) {
    int d = ei[E + e];
    int t = et[e];
    atomicAdd(&cnt[d * NREL + t], 1);
  }
}

__global__ void k_scan_reduce(const int* __restrict__ cnt, int* __restrict__ sums, int n) {
  __shared__ int sd[256];
  int base = blockIdx.x * 4096;
  int t = threadIdx.x;
  int acc = 0;
  for (int i = t; i < 4096; i += 256) {
    int idx = base + i;
    if (idx < n) acc += cnt[idx];
  }
  sd[t] = acc; __syncthreads();
  for (int s = 128; s > 0; s >>= 1) {
    if (t < s) sd[t] += sd[t + s];
    __syncthreads();
  }
  if (t == 0) sums[blockIdx.x] = sd[0];
}

// exclusive scan of up to 128 block sums, parallel
__global__ void k_scan_top(int* sums, int nb) {
  __shared__ int sd[128];
  int t = threadIdx.x;
  int v = (t < nb) ? sums[t] : 0;
  sd[t] = v; __syncthreads();
  for (int s = 1; s < 128; s <<= 1) {
    int u = (t >= s) ? sd[t - s] : 0;
    __syncthreads();
    sd[t] += u;
    __syncthreads();
  }
  if (t < nb) sums[t] = sd[t] - v;  // exclusive
}

__global__ void k_scan_final(const int* __restrict__ cnt, const int* __restrict__ sums,
                             int* __restrict__ offs, int* __restrict__ cur,
                             int n, int E) {
  __shared__ int sd[256];
  int base = blockIdx.x * 4096;
  int t = threadIdx.x;
  int run = sums[blockIdx.x];
  for (int c = 0; c < 16; c++) {
    int idx = base + c * 256 + t;
    int v = (idx < n) ? cnt[idx] : 0;
    sd[t] = v; __syncthreads();
    for (int s = 1; s < 256; s <<= 1) {
      int u = (t >= s) ? sd[t - s] : 0;
      __syncthreads();
      sd[t] += u;
      __syncthreads();
    }
    if (idx < n) {
      int e0 = run + sd[t] - v;  // exclusive
      offs[idx] = e0;
      cur[idx] = e0;
    }
    run += sd[255];
    __syncthreads();
  }
  if (blockIdx.x == 0 && t == 0) offs[n] = E;
}

__global__ void k_scatter(const int* __restrict__ ei, const int* __restrict__ et,
                          int* __restrict__ cursor, int* __restrict__ pk, int E) {
  int e = blockIdx.x * 256 + threadIdx.x;
  if (e < E) {
    int s = ei[e];       // src < 50000 fits in 16 bits
    int d = ei[E + e];
    int t = et[e];
    int pos = atomicAdd(&cursor[d * NREL + t], 1);
    pk[pos] = s | (t << 16);
  }
}

// ======================= per-layer kernels =======================

// Blocks 0..63: split Wcat into fragment-major bf16 hi/lo.
//   Frag id = (n16*4 + kc)*64 + l: n = n16*16 + (l&15), k = kc*32 + (l>>4)*8 + j,
//   value = W[r=n>>7][c=k][d=n&127].
// Block 64: qk fragment group (n16 index 64): n' = l&15;
//   n'<8 -> wq[n'][k] = dot(W[n'][k][:], q); n'>=8 -> wk[n'-8][k].
__global__ void k_wprep(const float* __restrict__ W, const float* __restrict__ q,
                        const float* __restrict__ kk, short* __restrict__ Wfh,
                        short* __restrict__ Wfl) {
  int b = blockIdx.x;
  if (b < 64) {
    int id = b * 256 + threadIdx.x;  // 0..16383
    int l = id & 63;
    int kc = (id >> 6) & 3;
    int n16 = id >> 8;
    int n = n16 * 16 + (l & 15);      // 0..1023
    int r = n >> 7, nn = n & 127;
    int k0 = kc * 32 + (l >> 4) * 8;  // 0..127
    short8 vh, vl;
#pragma unroll
    for (int j = 0; j < 8; j++) {
      float v = W[((size_t)r * DIM + k0 + j) * DIM + nn];
      short h = f2bf(v);
      vh[j] = h;
      vl[j] = f2bf(v - bf2f(h));
    }
    ((short8*)Wfh)[id] = vh;
    ((short8*)Wfl)[id] = vl;
  } else {
    int tid = threadIdx.x;
    int kc = tid >> 6, l = tid & 63;
    int np = l & 15;
    int k0 = kc * 32 + (l >> 4) * 8;
    const float* vec = (np < 8) ? q : kk;
    const float* wbase = W + ((size_t)(np & 7) * DIM) * DIM;
    short8 vh, vl;
#pragma unroll
    for (int j = 0; j < 8; j++) {
      const float* wrow = wbase + (size_t)(k0 + j) * DIM;
      float acc = 0.f;
#pragma unroll 8
      for (int d = 0; d < DIM; d++) acc += wrow[d] * vec[d];
      short h = f2bf(acc);
      vh[j] = h;
      vl[j] = f2bf(acc - bf2f(h));
    }
    int fid = (256 + kc) * 64 + l;
    ((short8*)Wfh)[fid] = vh;
    ((short8*)Wfl)[fid] = vl;
  }
}

// ======================= k_xr: xr = hin @ Wcat + fused qp/kp =======================
// [M=50000,K=128] @ [128,1024] -> fp32 xr [M][1024].  Block = 64m x 256n tile;
// 4 waves, wave w covers n in [nb*256 + w*64, +64).  A staged in LDS as
// pre-split bf16 hi/lo planes, 272B padded pitch (2-way banks = free).
// Wave 0 of nb==0 blocks also computes qp/kp via the 65th fragment group.
#define APITCH 272

__global__ __launch_bounds__(256, 3) void k_xr(
    const float* __restrict__ A, const short* __restrict__ Wfh,
    const short* __restrict__ Wfl, float* __restrict__ xr,
    float* __restrict__ qp, float* __restrict__ kp, int M, int nmt) {
  __shared__ char sAh[64 * APITCH];
  __shared__ char sAl[64 * APITCH];
  // bijective XCD chunking: nmt*4 % 8 == 0; nb fastest within an XCD chunk
  int lin = blockIdx.x;
  int nwg8 = (nmt * 4) >> 3;
  int g = (lin & 7) * nwg8 + (lin >> 3);
  int mt0 = g >> 2, nb = g & 3;
  int m0 = mt0 * 64;
  int t = threadIdx.x, w = t >> 6, l = t & 63;

  // ---- stage A tile: 64 rows x 128 fp32 -> bf16 hi/lo planes ----
  {
    int row = t >> 2, q4 = t & 3;
    int m = m0 + row;
    const float4* src = (const float4*)(A + (size_t)m * DIM + q4 * 32);
    float4 z = make_float4(0.f, 0.f, 0.f, 0.f);
#pragma unroll
    for (int u = 0; u < 4; u++) {
      float4 va = (m < M) ? src[2 * u] : z;
      float4 vb = (m < M) ? src[2 * u + 1] : z;
      float vv[8] = {va.x, va.y, va.z, va.w, vb.x, vb.y, vb.z, vb.w};
      short8 hh, ll;
#pragma unroll
      for (int j = 0; j < 8; j++) {
        short h = f2bf(vv[j]);
        hh[j] = h;
        ll[j] = f2bf(vv[j] - bf2f(h));
      }
      int off = row * APITCH + (q4 * 4 + u) * 16;
      *(short8*)(sAh + off) = hh;
      *(short8*)(sAl + off) = ll;
    }
  }
  __syncthreads();

  f32x4 acc[4][4];
  f32x4 accqk[4];
  f32x4 zero = {0.f, 0.f, 0.f, 0.f};
#pragma unroll
  for (int mt = 0; mt < 4; mt++) {
#pragma unroll
    for (int nt = 0; nt < 4; nt++) acc[mt][nt] = zero;
    accqk[mt] = zero;
  }

  int r16 = l & 15, hi16 = l >> 4;
  int n16base = nb * 16 + w * 4;
  int doqk = (w == 0 && nb == 0);
#pragma unroll
  for (int kc = 0; kc < 4; kc++) {
    short8 fsh[4], fsl[4];
#pragma unroll
    for (int mt = 0; mt < 4; mt++) {
      int row = mt * 16 + r16;
      int off = row * APITCH + (kc * 4 + hi16) * 16;
      fsh[mt] = *(const short8*)(sAh + off);
      fsl[mt] = *(const short8*)(sAl + off);
    }
#pragma unroll
    for (int nt = 0; nt < 4; nt++) {
      size_t fid = ((size_t)(n16base + nt) * 4 + kc) * 64 + l;
      short8 ah = ((const short8*)Wfh)[fid];
      short8 al = ((const short8*)Wfl)[fid];
#pragma unroll
      for (int mt = 0; mt < 4; mt++) {
        acc[mt][nt] = __builtin_amdgcn_mfma_f32_16x16x32_bf16(ah, fsh[mt], acc[mt][nt], 0, 0, 0);
        acc[mt][nt] = __builtin_amdgcn_mfma_f32_16x16x32_bf16(ah, fsl[mt], acc[mt][nt], 0, 0, 0);
        acc[mt][nt] = __builtin_amdgcn_mfma_f32_16x16x32_bf16(al, fsh[mt], acc[mt][nt], 0, 0, 0);
      }
    }
    if (doqk) {
      size_t fid = (size_t)(256 + kc) * 64 + l;
      short8 bh = ((const short8*)Wfh)[fid];
      short8 bl = ((const short8*)Wfl)[fid];
#pragma unroll
      for (int mt = 0; mt < 4; mt++) {
        accqk[mt] = __builtin_amdgcn_mfma_f32_16x16x32_bf16(bh, fsh[mt], accqk[mt], 0, 0, 0);
        accqk[mt] = __builtin_amdgcn_mfma_f32_16x16x32_bf16(bh, fsl[mt], accqk[mt], 0, 0, 0);
        accqk[mt] = __builtin_amdgcn_mfma_f32_16x16x32_bf16(bl, fsh[mt], accqk[mt], 0, 0, 0);
      }
    }
  }
  // ---- epilogue: D col(l&15)=m, row((l>>4)*4+j)=n ----
#pragma unroll
  for (int mt = 0; mt < 4; mt++) {
    int m = m0 + mt * 16 + r16;
    if (m >= M) continue;
#pragma unroll
    for (int nt = 0; nt < 4; nt++) {
      int n = nb * 256 + w * 64 + nt * 16 + hi16 * 4;
      f32x4 a = acc[mt][nt];
      float4 o; o.x = a.x; o.y = a.y; o.z = a.z; o.w = a.w;
      *(float4*)(xr + (size_t)m * NOUT + n) = o;
    }
    if (doqk) {
      // accqk row (hi16*4+j): 0-7 = qp[m][r], 8-15 = kp[m][r]
      float* dst = (hi16 < 2) ? (qp + (size_t)m * NREL + (hi16 & 1) * 4)
                              : (kp + (size_t)m * NREL + (hi16 & 1) * 4);
      f32x4 a = accqk[mt];
      float4 o; o.x = a.x; o.y = a.y; o.z = a.z; o.w = a.w;
      *(float4*)dst = o;
    }
  }
}

// ======================= k_agg_out: online softmax + gather-aggregate ==============
// One wave per dst node. out[n][c] = relu_opt( sum_e alpha_e * xr[src_e][t_e*128+c] + b[c] )
__global__ void k_agg_out(const float* __restrict__ xr, const float* __restrict__ qp,
                          const float* __restrict__ kp, const int* __restrict__ offs,
                          const int* __restrict__ pk, const float* __restrict__ bias,
                          float* __restrict__ out, int N, int relu) {
  int wid = (blockIdx.x * blockDim.x + threadIdx.x) >> 6;
  int lane = threadIdx.x & 63;
  if (wid >= N) return;
  int base = wid * NREL;
  int start = offs[base], end = offs[base + NREL];
  float a0 = 0.f, a1 = 0.f;
  if (start < end) {
    // ---- sweep 1: online (max, sum) per lane, then wave merge ----
    float m = -1e30f, s = 0.f;
    for (int i = start + lane; i < end; i += 64) {
      int p = pk[i];
      int src = p & 0xffff, tt = p >> 16;
      float a = qp[base + tt] + kp[src * NREL + tt];
      a = (a > 0.f) ? a : NEG_SLOPE * a;
      float mn = fmaxf(m, a);
      s = s * __expf(m - mn) + __expf(a - mn);
      m = mn;
    }
    for (int d = 32; d > 0; d >>= 1) {
      float mo = __shfl_xor(m, d);
      float so = __shfl_xor(s, d);
      float mn = fmaxf(m, mo);
      s = s * __expf(m - mn) + so * __expf(mo - mn);
      m = mn;
    }
    float inv = 1.f / (s + 1e-16f);
    // ---- sweep 2: weighted gather, 4-deep ----
    int i = start;
    for (; i + 4 <= end; i += 4) {
      int p0 = pk[i], p1 = pk[i + 1], p2 = pk[i + 2], p3 = pk[i + 3];
      float2 xv0 = ((const float2*)(xr + (((size_t)(p0 & 0xffff)) * NREL + (p0 >> 16)) * DIM))[lane];
      float2 xv1 = ((const float2*)(xr + (((size_t)(p1 & 0xffff)) * NREL + (p1 >> 16)) * DIM))[lane];
      float2 xv2 = ((const float2*)(xr + (((size_t)(p2 & 0xffff)) * NREL + (p2 >> 16)) * DIM))[lane];
      float2 xv3 = ((const float2*)(xr + (((size_t)(p3 & 0xffff)) * NREL + (p3 >> 16)) * DIM))[lane];
      float aa0 = qp[base + (p0 >> 16)] + kp[(p0 & 0xffff) * NREL + (p0 >> 16)];
      float aa1 = qp[base + (p1 >> 16)] + kp[(p1 & 0xffff) * NREL + (p1 >> 16)];
      float aa2 = qp[base + (p2 >> 16)] + kp[(p2 & 0xffff) * NREL + (p2 >> 16)];
      float aa3 = qp[base + (p3 >> 16)] + kp[(p3 & 0xffff) * NREL + (p3 >> 16)];
      aa0 = (aa0 > 0.f) ? aa0 : NEG_SLOPE * aa0;
      aa1 = (aa1 > 0.f) ? aa1 : NEG_SLOPE * aa1;
      aa2 = (aa2 > 0.f) ? aa2 : NEG_SLOPE * aa2;
      aa3 = (aa3 > 0.f) ? aa3 : NEG_SLOPE * aa3;
      float w0 = __expf(aa0 - m) * inv;
      float w1 = __expf(aa1 - m) * inv;
      float w2 = __expf(aa2 - m) * inv;
      float w3 = __expf(aa3 - m) * inv;
      a0 = fmaf(w0, xv0.x, a0); a1 = fmaf(w0, xv0.y, a1);
      a0 = fmaf(w1, xv1.x, a0); a1 = fmaf(w1, xv1.y, a1);
      a0 = fmaf(w2, xv2.x, a0); a1 = fmaf(w2, xv2.y, a1);
      a0 = fmaf(w3, xv3.x, a0); a1 = fmaf(w3, xv3.y, a1);
    }
    for (; i < end; i++) {
      int p = pk[i];
      int src = p & 0xffff, tt = p >> 16;
      float2 xv = ((const float2*)(xr + ((size_t)src * NREL + tt) * DIM))[lane];
      float a = qp[base + tt] + kp[src * NREL + tt];
      a = (a > 0.f) ? a : NEG_SLOPE * a;
      float wg = __expf(a - m) * inv;
      a0 = fmaf(wg, xv.x, a0);
      a1 = fmaf(wg, xv.y, a1);
    }
  }
  float2 bv = ((const float2*)bias)[lane];
  a0 += bv.x; a1 += bv.y;
  if (relu) { a0 = fmaxf(a0, 0.f); a1 = fmaxf(a1, 0.f); }
  float2 o; o.x = a0; o.y = a1;
  ((float2*)(out + (size_t)wid * DIM))[lane] = o;
}

// ======================= launcher =======================

extern "C" void kernel_launch(void* const* d_in, const int* in_sizes, int n_in,
                              void* d_out, int out_size, void* d_ws, size_t ws_size,
                              hipStream_t stream) {
  const float* x = (const float*)d_in[0];
  const int* ei = (const int*)d_in[1];
  const int* et = (const int*)d_in[2];
  const float* Wl3[3] = {(const float*)d_in[3], (const float*)d_in[7], (const float*)d_in[11]};
  const float* ql[3] = {(const float*)d_in[4], (const float*)d_in[8], (const float*)d_in[12]};
  const float* kl[3] = {(const float*)d_in[5], (const float*)d_in[9], (const float*)d_in[13]};
  const float* bl[3] = {(const float*)d_in[6], (const float*)d_in[10], (const float*)d_in[14]};
  float* out = (float*)d_out;

  char* w = (char*)d_ws;
  auto alloc = [&](size_t bytes) -> char* {
    char* p = w;
    w += (bytes + 255) & ~(size_t)255;
    return p;
  };
  const int NK = NNODES * NREL;
  float* xr = (float*)alloc((size_t)NNODES * NOUT * 4);  // 204.8 MB
  int* cnt = (int*)alloc((size_t)NK * 4);
  int* offs = (int*)alloc((size_t)(NK + 1) * 4);
  int* cursor = (int*)alloc((size_t)NK * 4);
  int* sums = (int*)alloc(256 * 4);
  int* pk = (int*)alloc((size_t)NEDGES * 4);
  float* qp = (float*)alloc((size_t)NNODES * NREL * 4);
  float* kp = (float*)alloc((size_t)NNODES * NREL * 4);
  short* Wfh = (short*)alloc((size_t)NFRAG * 16);
  short* Wfl = (short*)alloc((size_t)NFRAG * 16);
  float* h1 = (float*)alloc((size_t)NNODES * DIM * 4);
  float* h2 = (float*)alloc((size_t)NNODES * DIM * 4);

  // ---- build CSR sorted by (dst, etype), once (shared by all 3 layers) ----
  hipMemsetAsync(cnt, 0, (size_t)NK * 4, stream);
  k_hist<<<(NEDGES + 255) / 256, 256, 0, stream>>>(ei, et, cnt, NEDGES);
  int nchunk = (NK + 4095) / 4096;  // 98
  k_scan_reduce<<<nchunk, 256, 0, stream>>>(cnt, sums, NK);
  k_scan_top<<<1, 128, 0, stream>>>(sums, nchunk);
  k_scan_final<<<nchunk, 256, 0, stream>>>(cnt, sums, offs, cursor, NK, NEDGES);
  k_scatter<<<(NEDGES + 255) / 256, 256, 0, stream>>>(ei, et, cursor, pk, NEDGES);

  // ---- 3 RGAT layers ----
  const float* hin = x;
  float* houts[3] = {h1, h2, out};
  const int nmt = (NNODES + 63) / 64;  // 782; nmt*4 = 3128 divisible by 8
  for (int l = 0; l < 3; l++) {
    k_wprep<<<65, 256, 0, stream>>>(Wl3[l], ql[l], kl[l], Wfh, Wfl);
    k_xr<<<nmt * 4, 256, 0, stream>>>(hin, Wfh, Wfl, xr, qp, kp, NNODES, nmt);
    k_agg_out<<<(NNODES + 3) / 4, 256, 0, stream>>>(xr, qp, kp, offs, pk, bl[l],
                                                    houts[l], NNODES, l < 2 ? 1 : 0);
    hin = houts[l];
  }
}